// Round 21
// baseline (864.134 us; speedup 1.0000x reference)
//
#include <hip/hip_runtime.h>
#include <math.h>

#define NROWS 16384      // 32*512
#define DDIM  512
#define NE    4096
#define NZ    (NROWS * DDIM)
#define MAXC  128            // per-row collected-candidate cap
#define MARGIN 2e-3f         // >= needed 1.45e-3 + 2*bf16ulp slack (proof in k_mfma epi)

typedef __attribute__((ext_vector_type(8))) short bf16x8;
typedef __attribute__((ext_vector_type(4))) float f32x4;

__device__ __forceinline__ float sqr_rn(float x) { return __fmul_rn(x, x); }
__device__ __forceinline__ ushort f2bf(float f) {   // RNE f32->bf16
    const unsigned u = __float_as_uint(f);
    return (ushort)((u + 0x7fffu + ((u >> 16) & 1u)) >> 16);
}
__device__ __forceinline__ unsigned pack2(float a, float b) {
    return (unsigned)f2bf(a) | ((unsigned)f2bf(b) << 16);
}
// order-preserving bf16 key: key16 monotone in value (negatives first)
__device__ __forceinline__ unsigned ordkey(float s, int col) {
    const ushort b = f2bf(s);
    const ushort key16 = (b & 0x8000) ? (ushort)~b : (ushort)(b | 0x8000);
    return ((unsigned)key16 << 16) | (unsigned)col;    // col fits 12 bits
}
__device__ __forceinline__ float dec_key(unsigned p) {
    const ushort key16 = (ushort)(p >> 16);
    const ushort b = (key16 & 0x8000) ? (ushort)(key16 & 0x7fff) : (ushort)~key16;
    return __uint_as_float((unsigned)b << 16);
}

// ---------------- kernel 1: fused prep (Z: numpy-exact znorm + bf16; E: bnorm + bf16) --
__global__ void k_prep(const float* __restrict__ z, const float* __restrict__ emb,
                       ushort* __restrict__ zh, ushort* __restrict__ eh,
                       float* __restrict__ znorm, float* __restrict__ bnorm,
                       unsigned* __restrict__ counts) {
    if (blockIdx.x < 1024) {            // ---- E role: 4096 codes x 1 wave
        const int lane = threadIdx.x & 63;
        const int c = (int)((blockIdx.x * 256 + threadIdx.x) >> 6);
        const float4* p = (const float4*)(emb + (size_t)c * DDIM);
        const float4 v0 = p[lane * 2], v1 = p[lane * 2 + 1];
        uint4 w; w.x = pack2(v0.x, v0.y); w.y = pack2(v0.z, v0.w);
        w.z = pack2(v1.x, v1.y); w.w = pack2(v1.z, v1.w);
        *(uint4*)(eh + (size_t)c * DDIM + lane * 8) = w;
        float s = v0.x*v0.x + v0.y*v0.y + v0.z*v0.z + v0.w*v0.w
                + v1.x*v1.x + v1.y*v1.y + v1.z*v1.z + v1.w*v1.w;
        #pragma unroll
        for (int m = 32; m; m >>= 1) s += __shfl_xor(s, m);
        if (lane == 0) { bnorm[c] = s; counts[c] = 0u; }
    } else {                            // ---- Z role: numpy-exact pairwise znorm
        const int t = (int)((blockIdx.x - 1024) * 256 + threadIdx.x);   // 0..65535
        const int row = t >> 2, blk = t & 3;
        const float4* p = (const float4*)(z + (size_t)row * DDIM + blk * 128);
        ushort* zo = zh + (size_t)row * DDIM + blk * 128;
        float4 v0 = p[0], v1 = p[1];
        {
            uint4 w; w.x = pack2(v0.x, v0.y); w.y = pack2(v0.z, v0.w);
            w.z = pack2(v1.x, v1.y); w.w = pack2(v1.z, v1.w);
            *(uint4*)zo = w;
        }
        float r[8];
        r[0] = sqr_rn(v0.x); r[1] = sqr_rn(v0.y); r[2] = sqr_rn(v0.z); r[3] = sqr_rn(v0.w);
        r[4] = sqr_rn(v1.x); r[5] = sqr_rn(v1.y); r[6] = sqr_rn(v1.z); r[7] = sqr_rn(v1.w);
        #pragma unroll
        for (int i = 1; i < 16; ++i) {
            v0 = p[2 * i]; v1 = p[2 * i + 1];
            uint4 w; w.x = pack2(v0.x, v0.y); w.y = pack2(v0.z, v0.w);
            w.z = pack2(v1.x, v1.y); w.w = pack2(v1.z, v1.w);
            *(uint4*)(zo + i * 8) = w;
            r[0] = __fadd_rn(r[0], sqr_rn(v0.x)); r[1] = __fadd_rn(r[1], sqr_rn(v0.y));
            r[2] = __fadd_rn(r[2], sqr_rn(v0.z)); r[3] = __fadd_rn(r[3], sqr_rn(v0.w));
            r[4] = __fadd_rn(r[4], sqr_rn(v1.x)); r[5] = __fadd_rn(r[5], sqr_rn(v1.y));
            r[6] = __fadd_rn(r[6], sqr_rn(v1.z)); r[7] = __fadd_rn(r[7], sqr_rn(v1.w));
        }
        const float B = __fadd_rn(__fadd_rn(__fadd_rn(r[0], r[1]), __fadd_rn(r[2], r[3])),
                                  __fadd_rn(__fadd_rn(r[4], r[5]), __fadd_rn(r[6], r[7])));
        const float s01 = __fadd_rn(B, __shfl_xor(B, 1));     // in-wave quad reduce
        const float zn  = __fadd_rn(s01, __shfl_xor(s01, 2)); // ((B0+B1)+(B2+B3))
        if (blk == 0) znorm[row] = zn;
    }
}

// ---------------- kernel 2: bf16 MFMA GEMM, dbuf core + top2-digest epilogue -----------
// grid (128, 32), block 256 = 4 waves (2x2 of 64x64). Tile 128x128, BK=32, 32KB LDS.
// Main loop = R20-verified (dbuf, 1 barrier/K-step, early-issue prefetch; 148us).
// Epilogue now writes a 12.5MB digest instead of the 128MB sbuf (R20: WRITE_SIZE 139MB
// was first-order): per (row, 64-col blk): blkmin f32 + u64{top2 ordkeys} with
// cnt=#{f32 s <= blkmin+MARGIN} (ballot+popcount, straight-line, no atomics).
// CONTAINMENT PROOF: let N = {c: s(c) <= gmin+1.45e-3} (needed set). If cnt <= 2 then
// N(cap)blk is within the bf16-ordered top-2: x in N not in top-2 => exist y,z with
// bf16 <= bf16(x) => f32 y,z <= x + 2*bf16ulp <= blkmin + MARGIN => cnt >= 3. If
// cnt >= 3, k_pg takes ALL 64 codes of the block. Winner never lost.
__global__ __launch_bounds__(256) void k_mfma(const ushort* __restrict__ zh,
                                              const ushort* __restrict__ eh,
                                              const float* __restrict__ bnorm,
                                              unsigned long long* __restrict__ cand2,
                                              float* __restrict__ rowblkmin) {
    __shared__ ushort Af[2][8 * 512];   // 2 x 8KB
    __shared__ ushort Bf[2][8 * 512];
    const int tid = threadIdx.x;
    const int lane = tid & 63;
    const int w = tid >> 6;
    const int wrow = (w >> 1) * 64, wcol = (w & 1) * 64;
    const int rbase = blockIdx.x * 128, cbase = blockIdx.y * 128;
    const int sr = tid >> 1, sh = tid & 1;            // staging: row 0..127, k-half 0..1
    const int g  = sr >> 4, r15 = sr & 15;            // staging chunk, row-in-chunk
    const int r16 = lane & 15, g4 = (lane >> 4) * 4;  // frag row/col, k-subgroup
    const int soff = g * 512 + r15 * 8 + sh * 4;      // LDS staging offset (ushorts)

    const ushort* ga = zh + (size_t)(rbase + sr) * DDIM + sh * 16;   // k=0 base
    const ushort* gb = eh + (size_t)(cbase + sr) * DDIM + sh * 16;

    f32x4 acc[4][4];
    #pragma unroll
    for (int i = 0; i < 4; ++i)
        #pragma unroll
        for (int j = 0; j < 4; ++j) acc[i][j] = (f32x4){0.f, 0.f, 0.f, 0.f};

    // prologue: load tile 0 and stage into buf 0
    {
        const uint4 qa0 = *(const uint4*)ga;
        const uint4 qa1 = *(const uint4*)(ga + 8);
        const uint4 qb0 = *(const uint4*)gb;
        const uint4 qb1 = *(const uint4*)(gb + 8);
        ushort* pa = &Af[0][soff];
        *(uint2*)(pa +   0) = make_uint2(qa0.x, qa0.y);
        *(uint2*)(pa + 128) = make_uint2(qa0.z, qa0.w);
        *(uint2*)(pa + 256) = make_uint2(qa1.x, qa1.y);
        *(uint2*)(pa + 384) = make_uint2(qa1.z, qa1.w);
        ushort* pb = &Bf[0][soff];
        *(uint2*)(pb +   0) = make_uint2(qb0.x, qb0.y);
        *(uint2*)(pb + 128) = make_uint2(qb0.z, qb0.w);
        *(uint2*)(pb + 256) = make_uint2(qb1.x, qb1.y);
        *(uint2*)(pb + 384) = make_uint2(qb1.z, qb1.w);
    }
    __syncthreads();

    for (int kb = 0; kb < DDIM; kb += 32) {
        const int cur = (kb >> 5) & 1;
        const bool more = (kb + 32 < DDIM);
        uint4 na0, na1, nb0, nb1;
        if (more) {     // issue next-tile loads first: latency hides under MFMA
            na0 = *(const uint4*)(ga + kb + 32);
            na1 = *(const uint4*)(ga + kb + 40);
            nb0 = *(const uint4*)(gb + kb + 32);
            nb1 = *(const uint4*)(gb + kb + 40);
        }
        bf16x8 af[4], bf[4];
        #pragma unroll
        for (int f = 0; f < 4; ++f) {
            af[f] = *(const bf16x8*)&Af[cur][((wrow >> 4) + f) * 512 + lane * 8];
            bf[f] = *(const bf16x8*)&Bf[cur][((wcol >> 4) + f) * 512 + lane * 8];
        }
        #pragma unroll
        for (int fi = 0; fi < 4; ++fi)
            #pragma unroll
            for (int fj = 0; fj < 4; ++fj)
                acc[fi][fj] = __builtin_amdgcn_mfma_f32_16x16x32_bf16(
                    af[fi], bf[fj], acc[fi][fj], 0, 0, 0);
        if (more) {     // stage tile t+1 (safe: its readers finished pre-prev-barrier)
            ushort* pa = &Af[cur ^ 1][soff];
            *(uint2*)(pa +   0) = make_uint2(na0.x, na0.y);
            *(uint2*)(pa + 128) = make_uint2(na0.z, na0.w);
            *(uint2*)(pa + 256) = make_uint2(na1.x, na1.y);
            *(uint2*)(pa + 384) = make_uint2(na1.z, na1.w);
            ushort* pb = &Bf[cur ^ 1][soff];
            *(uint2*)(pb +   0) = make_uint2(nb0.x, nb0.y);
            *(uint2*)(pb + 128) = make_uint2(nb0.z, nb0.w);
            *(uint2*)(pb + 256) = make_uint2(nb1.x, nb1.y);
            *(uint2*)(pb + 384) = make_uint2(nb1.z, nb1.w);
            __syncthreads();
        }
    }

    // C/D layout: value (fi,fj,r) -> row = wrow+fi*16+g4+r, col = wcol+fj*16+r16
    float bn[4];
    #pragma unroll
    for (int fj = 0; fj < 4; ++fj) bn[fj] = bnorm[cbase + wcol + fj * 16 + r16];
    const unsigned long long gmask = 0xFFFFULL << ((lane >> 4) * 16);

    #pragma unroll
    for (int fi = 0; fi < 4; ++fi) {
        #pragma unroll
        for (int r = 0; r < 4; ++r) {
            const int row = rbase + wrow + fi * 16 + g4 + r;
            float s[4];
            #pragma unroll
            for (int fj = 0; fj < 4; ++fj) s[fj] = fmaf(-2.f, acc[fi][fj][r], bn[fj]);
            float m = fminf(fminf(s[0], s[1]), fminf(s[2], s[3]));
            #pragma unroll
            for (int x = 1; x < 16; x <<= 1) m = fminf(m, __shfl_xor(m, x));  // grp min
            const float thrB = m + MARGIN;
            int cnt = 0;
            unsigned k[4];
            #pragma unroll
            for (int fj = 0; fj < 4; ++fj) {
                cnt += __popcll(__ballot(s[fj] <= thrB) & gmask);
                k[fj] = ordkey(s[fj], cbase + wcol + fj * 16 + r16);
            }
            unsigned a0 = min(k[0], k[1]), a1 = max(k[0], k[1]);
            unsigned b0 = min(k[2], k[3]), b1 = max(k[2], k[3]);
            unsigned m1 = min(a0, b0);
            unsigned m2 = min(max(a0, b0), min(a1, b1));
            #pragma unroll
            for (int x = 1; x < 16; x <<= 1) {
                const unsigned o1 = __shfl_xor(m1, x), o2 = __shfl_xor(m2, x);
                const unsigned n1 = min(m1, o1);
                m2 = min(max(m1, o1), min(m2, o2));
                m1 = n1;
            }
            if (r16 == 0) {
                const int slot = (int)blockIdx.y * 2 + (w & 1);
                rowblkmin[(size_t)row * 64 + slot] = m;
                m2 = (m2 & 0xFFFF0FFFu) | ((unsigned)min(cnt, 15) << 12);  // cnt in spare bits
                cand2[(size_t)row * 64 + slot] = ((unsigned long long)m1 << 32) | m2;
            }
        }
    }
}

// ---------------- exact numpy chain: sequential ascending-k FMA + exact bucketing ------
__device__ __forceinline__ unsigned long long exact_key(const float4* __restrict__ zp4,
                                                        const float* __restrict__ emb,
                                                        const float* __restrict__ bnorm,
                                                        float zn, int c) {
    const float4* ep4 = (const float4*)(emb + (size_t)c * DDIM);
    float acc = 0.f;
    #pragma unroll 8
    for (int q = 0; q < DDIM / 4; ++q) {
        const float4 zv = zp4[q];
        const float4 ev = ep4[q];
        acc = fmaf(zv.x, ev.x, acc);
        acc = fmaf(zv.y, ev.y, acc);
        acc = fmaf(zv.z, ev.z, acc);
        acc = fmaf(zv.w, ev.w, acc);
    }
    const float s = __fsub_rn(__fadd_rn(zn, bnorm[c]), __fmul_rn(2.f, acc));
    return ((unsigned long long)__float_as_uint(s) << 32) | (unsigned)c;
}

// ---------------- kernel 3: digest pick + exact resolve + gather + STE ----------------
// one wave per row; reads rowblkmin (4MB) + cand2 (8MB digests); candidates only in
// per-wave LDS; writes out. cnt>2 flagged block -> take all 64 of its codes.
__global__ void k_pg(const unsigned long long* __restrict__ cand2,
                     const float* __restrict__ rowblkmin,
                     const float* __restrict__ z, const float* __restrict__ emb,
                     const float* __restrict__ znorm, const float* __restrict__ bnorm,
                     float* __restrict__ out, unsigned* __restrict__ counts,
                     float* __restrict__ d2buf) {
    __shared__ int candL[4][MAXC];
    const int lane = threadIdx.x & 63;
    const int w = threadIdx.x >> 6;
    const int row = blockIdx.x * 4 + w;

    const float bm = rowblkmin[(size_t)row * 64 + lane];
    float gmin = bm;
    #pragma unroll
    for (int m = 32; m; m >>= 1) gmin = fminf(gmin, __shfl_xor(gmin, m));
    const float thr = gmin + MARGIN;
    unsigned long long bmask = __ballot(bm <= thr);   // expected ~1.3 blocks
    int kc = 0;                    // uniform across lanes
    bool fullscan = false;
    while (bmask) {
        const int b = __builtin_ctzll(bmask); bmask &= bmask - 1;
        const unsigned long long cd = cand2[(size_t)row * 64 + b];   // uniform load
        const unsigned p1 = (unsigned)(cd >> 32), p2 = (unsigned)cd;
        const int cnt = (int)((p2 >> 12) & 0xFu);
        if (cnt > 2) {                         // take whole block (64 codes)
            if (kc + 64 <= MAXC) candL[w][kc + lane] = b * 64 + lane;
            else fullscan = true;
            kc += 64;
        } else {
            if (dec_key(p1) <= thr) {          // uniform condition
                if (lane == 0 && kc < MAXC) candL[w][kc] = (int)(p1 & 0xFFFu);
                ++kc;
            }
            if (dec_key(p2) <= thr) {
                if (lane == 0 && kc < MAXC) candL[w][kc] = (int)(p2 & 0xFFFu);
                ++kc;
            }
        }
    }
    if (kc > MAXC) fullscan = true;

    int id;
    if (!fullscan && kc == 1) {
        id = candL[w][0] & (NE - 1);
    } else {
        const float zn = znorm[row];
        const float4* zp4 = (const float4*)(z + (size_t)row * DDIM);
        unsigned long long best = ~0ULL;
        if (!fullscan) {
            for (int i = lane; i < kc; i += 64)
                best = min(best, exact_key(zp4, emb, bnorm, zn, candL[w][i] & (NE - 1)));
        } else {        // overflow (rare): exact scan of all codes
            for (int c = lane; c < NE; c += 64) {
                const unsigned long long kk = exact_key(zp4, emb, bnorm, zn, c);
                if (kk < best) best = kk;
            }
        }
        #pragma unroll
        for (int m = 32; m; m >>= 1) {
            const unsigned long long ov = __shfl_xor(best, m);
            if (ov < best) best = ov;
        }
        id = (int)(__shfl(best, 0) & (unsigned long long)(NE - 1));
    }

    const float* zp = z + (size_t)row * DDIM;
    const float* ep = emb + (size_t)id * DDIM;
    float* op = out + 1 + (size_t)row * DDIM;
    float d2 = 0.f;
    #pragma unroll
    for (int m = 0; m < 8; ++m) {
        const int k = m * 64 + lane;
        const float e = ep[k];
        const float zv = zp[k];
        const float t = e - zv;          // two-step rounding matches reference STE
        op[k] = zv + t;
        d2 = fmaf(t, t, d2);
    }
    #pragma unroll
    for (int m = 32; m; m >>= 1) d2 += __shfl_xor(d2, m);
    if (lane == 0) {
        atomicAdd(&counts[id], 1u);
        d2buf[row] = d2;
        out[1 + (size_t)NZ + row] = (float)id;
    }
}

// ---------------- kernel 4: finalize loss + perplexity ----------------
__global__ void k_final(const float* __restrict__ d2buf, const unsigned* __restrict__ counts,
                        float* __restrict__ out) {
    __shared__ double sh[256];
    __shared__ float  shf[256];
    const int tid = threadIdx.x;
    double ent = 0.0;
    for (int i = tid; i < NE; i += 256) {
        const double p = (double)counts[i] / (double)NROWS;
        ent += p * log(p + 1e-10);
    }
    float sse = 0.f;
    for (int i = tid; i < NROWS; i += 256) sse += d2buf[i];
    sh[tid] = ent; shf[tid] = sse;
    __syncthreads();
    for (int s = 128; s; s >>= 1) {
        if (tid < s) { sh[tid] += sh[tid + s]; shf[tid] += shf[tid + s]; }
        __syncthreads();
    }
    if (tid == 0) {
        out[0] = 1.25f * (shf[0] / (float)NZ);
        out[1 + (size_t)NZ + NROWS] = (float)exp(-sh[0]);
    }
}

extern "C" void kernel_launch(void* const* d_in, const int* in_sizes, int n_in,
                              void* d_out, int out_size, void* d_ws, size_t ws_size,
                              hipStream_t stream) {
    const float* z   = (const float*)d_in[0];
    const float* emb = (const float*)d_in[1];
    float* out = (float*)d_out;
    char* ws = (char*)d_ws;

    // zh/eh live inside out[1..NZ]: written by k_prep, read by k_mfma, and only
    // k_pg (strictly later in stream order) writes out -> no overlap anywhere.
    ushort* zh = (ushort*)(out + 4);                       // 16 MB
    ushort* eh = (ushort*)(out + 4 + 4194304);             //  4 MB

    size_t off = 0;
    float*    bnorm  = (float*)(ws + off); off += (size_t)NE * 4;          // 16KB
    unsigned* counts = (unsigned*)(ws + off); off += (size_t)NE * 4;       // 16KB
    float*    d2buf  = (float*)(ws + off); off += (size_t)NROWS * 4;       // 64KB
    float*    znorm  = (float*)(ws + off); off += (size_t)NROWS * 4;       // 64KB
    float*    rowblkmin = (float*)(ws + off); off += (size_t)NROWS * 64 * 4;  // 4MB
    unsigned long long* cand2 = (unsigned long long*)(ws + off);
    off += (size_t)NROWS * 64 * 8;                                         // 8MB
    // total ~12.5MB << proven ws

    k_prep<<<1280, 256, 0, stream>>>(z, emb, zh, eh, znorm, bnorm, counts);
    k_mfma<<<dim3(NROWS / 128, NE / 128), 256, 0, stream>>>(zh, eh, bnorm, cand2, rowblkmin);
    k_pg<<<NROWS / 4, 256, 0, stream>>>(cand2, rowblkmin, z, emb, znorm, bnorm, out, counts, d2buf);
    k_final<<<1, 256, 0, stream>>>(d2buf, counts, out);
}

// Round 22
// 389.704 us; speedup vs baseline: 2.2174x; 2.2174x over previous
//
#include <hip/hip_runtime.h>
#include <math.h>

#define NROWS 16384      // 32*512
#define DDIM  512
#define NE    4096
#define NZ    (NROWS * DDIM)
#define MAXC  64             // per-row kept-candidate cap (expected ~2)
#define MARGIN 2e-3f         // >= bound 2E + bucket + bf16 rounds ~ 1.4e-3

typedef __attribute__((ext_vector_type(8))) short bf16x8;
typedef __attribute__((ext_vector_type(4))) float f32x4;

__device__ __forceinline__ float sqr_rn(float x) { return __fmul_rn(x, x); }
__device__ __forceinline__ ushort f2bf(float f) {   // RNE f32->bf16
    const unsigned u = __float_as_uint(f);
    return (ushort)((u + 0x7fffu + ((u >> 16) & 1u)) >> 16);
}
__device__ __forceinline__ unsigned pack2(float a, float b) {
    return (unsigned)f2bf(a) | ((unsigned)f2bf(b) << 16);
}

// ---------------- kernel 1: fused prep (Z: numpy-exact znorm + bf16; E: bnorm + bf16) --
__global__ void k_prep(const float* __restrict__ z, const float* __restrict__ emb,
                       ushort* __restrict__ zh, ushort* __restrict__ eh,
                       float* __restrict__ znorm, float* __restrict__ bnorm,
                       unsigned* __restrict__ counts) {
    if (blockIdx.x < 1024) {            // ---- E role: 4096 codes x 1 wave
        const int lane = threadIdx.x & 63;
        const int c = (int)((blockIdx.x * 256 + threadIdx.x) >> 6);
        const float4* p = (const float4*)(emb + (size_t)c * DDIM);
        const float4 v0 = p[lane * 2], v1 = p[lane * 2 + 1];
        uint4 w; w.x = pack2(v0.x, v0.y); w.y = pack2(v0.z, v0.w);
        w.z = pack2(v1.x, v1.y); w.w = pack2(v1.z, v1.w);
        *(uint4*)(eh + (size_t)c * DDIM + lane * 8) = w;
        float s = v0.x*v0.x + v0.y*v0.y + v0.z*v0.z + v0.w*v0.w
                + v1.x*v1.x + v1.y*v1.y + v1.z*v1.z + v1.w*v1.w;
        #pragma unroll
        for (int m = 32; m; m >>= 1) s += __shfl_xor(s, m);
        if (lane == 0) { bnorm[c] = s; counts[c] = 0u; }
    } else {                            // ---- Z role: numpy-exact pairwise znorm
        const int t = (int)((blockIdx.x - 1024) * 256 + threadIdx.x);   // 0..65535
        const int row = t >> 2, blk = t & 3;
        const float4* p = (const float4*)(z + (size_t)row * DDIM + blk * 128);
        ushort* zo = zh + (size_t)row * DDIM + blk * 128;
        float4 v0 = p[0], v1 = p[1];
        {
            uint4 w; w.x = pack2(v0.x, v0.y); w.y = pack2(v0.z, v0.w);
            w.z = pack2(v1.x, v1.y); w.w = pack2(v1.z, v1.w);
            *(uint4*)zo = w;
        }
        float r[8];
        r[0] = sqr_rn(v0.x); r[1] = sqr_rn(v0.y); r[2] = sqr_rn(v0.z); r[3] = sqr_rn(v0.w);
        r[4] = sqr_rn(v1.x); r[5] = sqr_rn(v1.y); r[6] = sqr_rn(v1.z); r[7] = sqr_rn(v1.w);
        #pragma unroll
        for (int i = 1; i < 16; ++i) {
            v0 = p[2 * i]; v1 = p[2 * i + 1];
            uint4 w; w.x = pack2(v0.x, v0.y); w.y = pack2(v0.z, v0.w);
            w.z = pack2(v1.x, v1.y); w.w = pack2(v1.z, v1.w);
            *(uint4*)(zo + i * 8) = w;
            r[0] = __fadd_rn(r[0], sqr_rn(v0.x)); r[1] = __fadd_rn(r[1], sqr_rn(v0.y));
            r[2] = __fadd_rn(r[2], sqr_rn(v0.z)); r[3] = __fadd_rn(r[3], sqr_rn(v0.w));
            r[4] = __fadd_rn(r[4], sqr_rn(v1.x)); r[5] = __fadd_rn(r[5], sqr_rn(v1.y));
            r[6] = __fadd_rn(r[6], sqr_rn(v1.z)); r[7] = __fadd_rn(r[7], sqr_rn(v1.w));
        }
        const float B = __fadd_rn(__fadd_rn(__fadd_rn(r[0], r[1]), __fadd_rn(r[2], r[3])),
                                  __fadd_rn(__fadd_rn(r[4], r[5]), __fadd_rn(r[6], r[7])));
        const float s01 = __fadd_rn(B, __shfl_xor(B, 1));     // in-wave quad reduce
        const float zn  = __fadd_rn(s01, __shfl_xor(s01, 2)); // ((B0+B1)+(B2+B3))
        if (blk == 0) znorm[row] = zn;
    }
}

// ---------------- kernel 2: bf16 MFMA GEMM, direct-from-global fragments ---------------
// grid (128, 32), block 256 = 4 waves (2x2 of 64x64). Tile 128x128, BK=32, NO LDS.
// R20 diagnosis: LDS-issue-bound (8 ds_read_b128 + 16 ds_write_b64 per wave-K-step =
// 256 LDS-cyc/block vs 80 MFMA-cyc/SIMD -> MfmaUtil ~19%). Contiguous-k fragment layout
// (R13-verified absmax 0): lane l of a 16-row chunk holds row 16g+(l&15),
// k = kb+8*(l>>4)+{0..7} -> one contiguous 16B global load per lane. So fragments load
// DIRECTLY from global: no LDS, no ds_writes, no barriers. Same k-permutation for A and
// B => every MFMA multiplies matching k pairs => dot preserved (R13 proof + empirics).
// Next-step prefetch (8 frags in regs) hides L2 latency under 16 MFMAs.
// Epilogue (fetch-method-independent C/D layout) byte-identical to R20: straight-line
// packed uint2 sbuf stores + branch-free rowblkmin (R18 lesson: no atomics here).
__global__ __launch_bounds__(256) void k_mfma(const ushort* __restrict__ zh,
                                              const ushort* __restrict__ eh,
                                              const float* __restrict__ bnorm,
                                              ushort* __restrict__ sbuf,
                                              float* __restrict__ rowblkmin) {
    const int tid = threadIdx.x;
    const int lane = tid & 63;
    const int w = tid >> 6;
    const int wrow = (w >> 1) * 64, wcol = (w & 1) * 64;
    const int rbase = blockIdx.x * 128, cbase = blockIdx.y * 128;
    const int r16 = lane & 15, g4 = (lane >> 4) * 4;  // frag row/col, k-subgroup
    const int k8 = (lane >> 4) * 8;                   // contiguous-k lane offset

    // per-fragment global base addresses (ushort units)
    const ushort* pa[4];
    const ushort* pb[4];
    #pragma unroll
    for (int f = 0; f < 4; ++f) {
        pa[f] = zh + (size_t)(rbase + wrow + f * 16 + r16) * DDIM + k8;
        pb[f] = eh + (size_t)(cbase + wcol + f * 16 + r16) * DDIM + k8;
    }

    f32x4 acc[4][4];
    #pragma unroll
    for (int i = 0; i < 4; ++i)
        #pragma unroll
        for (int j = 0; j < 4; ++j) acc[i][j] = (f32x4){0.f, 0.f, 0.f, 0.f};

    bf16x8 caf[4], cbf[4];
    #pragma unroll
    for (int f = 0; f < 4; ++f) {       // step-0 fragments
        caf[f] = *(const bf16x8*)(pa[f]);
        cbf[f] = *(const bf16x8*)(pb[f]);
    }

    for (int kb = 0; kb < DDIM; kb += 32) {
        const bool more = (kb + 32 < DDIM);
        bf16x8 naf[4], nbf[4];
        if (more) {                     // prefetch next step; hides under MFMAs below
            #pragma unroll
            for (int f = 0; f < 4; ++f) {
                naf[f] = *(const bf16x8*)(pa[f] + kb + 32);
                nbf[f] = *(const bf16x8*)(pb[f] + kb + 32);
            }
        }
        #pragma unroll
        for (int fi = 0; fi < 4; ++fi)
            #pragma unroll
            for (int fj = 0; fj < 4; ++fj)
                acc[fi][fj] = __builtin_amdgcn_mfma_f32_16x16x32_bf16(
                    caf[fi], cbf[fj], acc[fi][fj], 0, 0, 0);
        if (more) {
            #pragma unroll
            for (int f = 0; f < 4; ++f) { caf[f] = naf[f]; cbf[f] = nbf[f]; }
        }
    }

    // C/D layout: value (fi,fj,r) -> row = wrow+fi*16+g4+r, col = wcol+fj*16+r16
    float bn[4];
    #pragma unroll
    for (int fj = 0; fj < 4; ++fj) bn[fj] = bnorm[cbase + wcol + fj * 16 + r16];

    #pragma unroll
    for (int fi = 0; fi < 4; ++fi) {
        #pragma unroll
        for (int r = 0; r < 4; ++r) {
            const int row = rbase + wrow + fi * 16 + g4 + r;
            float s[4];
            #pragma unroll
            for (int fj = 0; fj < 4; ++fj) s[fj] = fmaf(-2.f, acc[fi][fj][r], bn[fj]);
            uint2* sp = (uint2*)(sbuf + (size_t)row * NE + cbase + wcol);
            sp[r16] = make_uint2(pack2(s[0], s[1]), pack2(s[2], s[3]));
            float m = fminf(fminf(s[0], s[1]), fminf(s[2], s[3]));
            #pragma unroll
            for (int x = 1; x < 16; x <<= 1) m = fminf(m, __shfl_xor(m, x));  // 16-lane grp
            if (r16 == 0)
                rowblkmin[(size_t)row * 64 + blockIdx.y * 2 + (w & 1)] = m;
        }
    }
}

// ---------------- exact numpy chain: sequential ascending-k FMA + exact bucketing ------
__device__ __forceinline__ unsigned long long exact_key(const float4* __restrict__ zp4,
                                                        const float* __restrict__ emb,
                                                        const float* __restrict__ bnorm,
                                                        float zn, int c) {
    const float4* ep4 = (const float4*)(emb + (size_t)c * DDIM);
    float acc = 0.f;
    #pragma unroll 8
    for (int q = 0; q < DDIM / 4; ++q) {
        const float4 zv = zp4[q];
        const float4 ev = ep4[q];
        acc = fmaf(zv.x, ev.x, acc);
        acc = fmaf(zv.y, ev.y, acc);
        acc = fmaf(zv.z, ev.z, acc);
        acc = fmaf(zv.w, ev.w, acc);
    }
    const float s = __fsub_rn(__fadd_rn(zn, bnorm[c]), __fmul_rn(2.f, acc));
    return ((unsigned long long)__float_as_uint(s) << 32) | (unsigned)c;
}

// ---------------- kernel 3: guided pick + exact resolve + gather + STE ----------------
// one wave per row; reads rowblkmin (4MB) + only flagged sbuf segments (~1.3 x 128B/row);
// candidates live only in per-wave LDS (no cross-block races); writes out.
// sbuf in-64-block permutation: col = b*64 + (i&3)*16 + (i>>2).
__global__ void k_pg(const ushort* __restrict__ sbuf, const float* __restrict__ rowblkmin,
                     const float* __restrict__ z, const float* __restrict__ emb,
                     const float* __restrict__ znorm, const float* __restrict__ bnorm,
                     float* __restrict__ out, unsigned* __restrict__ counts,
                     float* __restrict__ d2buf) {
    __shared__ int candL[4][MAXC];
    __shared__ unsigned cntL[4];
    const int lane = threadIdx.x & 63;
    const int w = threadIdx.x >> 6;
    const int row = blockIdx.x * 4 + w;
    if (threadIdx.x < 4) cntL[threadIdx.x] = 0u;
    __syncthreads();

    const float bm = rowblkmin[(size_t)row * 64 + lane];
    float gmin = bm;
    #pragma unroll
    for (int m = 32; m; m >>= 1) gmin = fminf(gmin, __shfl_xor(gmin, m));
    const float thr = gmin + MARGIN;
    unsigned long long bmask = __ballot(bm <= thr);   // expected ~1.3 blocks
    while (bmask) {
        const int b = __builtin_ctzll(bmask); bmask &= bmask - 1;
        const float val = __uint_as_float(
            (unsigned)sbuf[(size_t)row * NE + b * 64 + lane] << 16);
        if (val <= thr) {
            const unsigned slot = atomicAdd(&cntL[w], 1u);
            if (slot < MAXC)
                candL[w][slot] = b * 64 + (lane & 3) * 16 + (lane >> 2);
        }
    }
    __syncthreads();

    const int cnt = (int)cntL[w];
    int id;
    if (cnt == 1) {
        id = candL[w][0] & (NE - 1);
    } else {
        const float zn = znorm[row];
        const float4* zp4 = (const float4*)(z + (size_t)row * DDIM);
        unsigned long long best = ~0ULL;
        if (cnt >= 2 && cnt <= MAXC) {
            if (lane < cnt)
                best = exact_key(zp4, emb, bnorm, zn, candL[w][lane] & (NE - 1));
        } else {             // cnt==0 (impossible) or overflow: exact scan of all codes
            for (int c = lane; c < NE; c += 64) {
                const unsigned long long k = exact_key(zp4, emb, bnorm, zn, c);
                if (k < best) best = k;
            }
        }
        #pragma unroll
        for (int m = 32; m; m >>= 1) {
            const unsigned long long ov = __shfl_xor(best, m);
            if (ov < best) best = ov;
        }
        id = (int)(__shfl(best, 0) & (unsigned long long)(NE - 1));
    }

    const float* zp = z + (size_t)row * DDIM;
    const float* ep = emb + (size_t)id * DDIM;
    float* op = out + 1 + (size_t)row * DDIM;
    float d2 = 0.f;
    #pragma unroll
    for (int m = 0; m < 8; ++m) {
        const int k = m * 64 + lane;
        const float e = ep[k];
        const float zv = zp[k];
        const float t = e - zv;          // two-step rounding matches reference STE
        op[k] = zv + t;
        d2 = fmaf(t, t, d2);
    }
    #pragma unroll
    for (int m = 32; m; m >>= 1) d2 += __shfl_xor(d2, m);
    if (lane == 0) {
        atomicAdd(&counts[id], 1u);
        d2buf[row] = d2;
        out[1 + (size_t)NZ + row] = (float)id;
    }
}

// ---------------- kernel 4: finalize loss + perplexity ----------------
__global__ void k_final(const float* __restrict__ d2buf, const unsigned* __restrict__ counts,
                        float* __restrict__ out) {
    __shared__ double sh[256];
    __shared__ float  shf[256];
    const int tid = threadIdx.x;
    double ent = 0.0;
    for (int i = tid; i < NE; i += 256) {
        const double p = (double)counts[i] / (double)NROWS;
        ent += p * log(p + 1e-10);
    }
    float sse = 0.f;
    for (int i = tid; i < NROWS; i += 256) sse += d2buf[i];
    sh[tid] = ent; shf[tid] = sse;
    __syncthreads();
    for (int s = 128; s; s >>= 1) {
        if (tid < s) { sh[tid] += sh[tid + s]; shf[tid] += shf[tid + s]; }
        __syncthreads();
    }
    if (tid == 0) {
        out[0] = 1.25f * (shf[0] / (float)NZ);
        out[1 + (size_t)NZ + NROWS] = (float)exp(-sh[0]);
    }
}

extern "C" void kernel_launch(void* const* d_in, const int* in_sizes, int n_in,
                              void* d_out, int out_size, void* d_ws, size_t ws_size,
                              hipStream_t stream) {
    const float* z   = (const float*)d_in[0];
    const float* emb = (const float*)d_in[1];
    float* out = (float*)d_out;
    char* ws = (char*)d_ws;

    // zh/eh live inside out[1..NZ]: written by k_prep, read by k_mfma, and only
    // k_pg (strictly later in stream order) writes out -> no overlap anywhere.
    ushort* zh = (ushort*)(out + 4);                       // 16 MB
    ushort* eh = (ushort*)(out + 4 + 4194304);             //  4 MB

    size_t off = 0;
    float*    bnorm  = (float*)(ws + off); off += (size_t)NE * 4;          // 16KB
    unsigned* counts = (unsigned*)(ws + off); off += (size_t)NE * 4;       // 16KB
    float*    d2buf  = (float*)(ws + off); off += (size_t)NROWS * 4;       // 64KB
    float*    znorm  = (float*)(ws + off); off += (size_t)NROWS * 4;       // 64KB
    ushort*   sbuf   = (ushort*)(ws + off); off += (size_t)NROWS * NE * 2; // 128MB
    float*    rowblkmin = (float*)(ws + off); off += (size_t)NROWS * 64 * 4; // 4MB
    // total ~132.5MB == R12/R19/R20's proven footprint

    k_prep<<<1280, 256, 0, stream>>>(z, emb, zh, eh, znorm, bnorm, counts);
    k_mfma<<<dim3(NROWS / 128, NE / 128), 256, 0, stream>>>(zh, eh, bnorm, sbuf, rowblkmin);
    k_pg<<<NROWS / 4, 256, 0, stream>>>(sbuf, rowblkmin, z, emb, znorm, bnorm, out, counts, d2buf);
    k_final<<<1, 256, 0, stream>>>(d2buf, counts, out);
}

// Round 23
// 320.216 us; speedup vs baseline: 2.6986x; 1.2170x over previous
//
#include <hip/hip_runtime.h>
#include <math.h>

#define NROWS 16384      // 32*512
#define DDIM  512
#define NE    4096
#define NZ    (NROWS * DDIM)
#define MAXC  64             // per-row kept-candidate cap (expected ~2)
#define MARGIN 2e-3f         // >= bound 2E + bucket + bf16 rounds ~ 1.4e-3

typedef __attribute__((ext_vector_type(8))) short bf16x8;
typedef __attribute__((ext_vector_type(4))) float f32x4;

__device__ __forceinline__ float sqr_rn(float x) { return __fmul_rn(x, x); }
__device__ __forceinline__ ushort f2bf(float f) {   // RNE f32->bf16
    const unsigned u = __float_as_uint(f);
    return (ushort)((u + 0x7fffu + ((u >> 16) & 1u)) >> 16);
}
__device__ __forceinline__ unsigned pack2(float a, float b) {
    return (unsigned)f2bf(a) | ((unsigned)f2bf(b) << 16);
}

// ---------------- kernel 1: fused prep (Z: numpy-exact znorm + bf16; E: bnorm + bf16) --
__global__ void k_prep(const float* __restrict__ z, const float* __restrict__ emb,
                       ushort* __restrict__ zh, ushort* __restrict__ eh,
                       float* __restrict__ znorm, float* __restrict__ bnorm,
                       unsigned* __restrict__ counts) {
    if (blockIdx.x < 1024) {            // ---- E role: 4096 codes x 1 wave
        const int lane = threadIdx.x & 63;
        const int c = (int)((blockIdx.x * 256 + threadIdx.x) >> 6);
        const float4* p = (const float4*)(emb + (size_t)c * DDIM);
        const float4 v0 = p[lane * 2], v1 = p[lane * 2 + 1];
        uint4 w; w.x = pack2(v0.x, v0.y); w.y = pack2(v0.z, v0.w);
        w.z = pack2(v1.x, v1.y); w.w = pack2(v1.z, v1.w);
        *(uint4*)(eh + (size_t)c * DDIM + lane * 8) = w;
        float s = v0.x*v0.x + v0.y*v0.y + v0.z*v0.z + v0.w*v0.w
                + v1.x*v1.x + v1.y*v1.y + v1.z*v1.z + v1.w*v1.w;
        #pragma unroll
        for (int m = 32; m; m >>= 1) s += __shfl_xor(s, m);
        if (lane == 0) { bnorm[c] = s; counts[c] = 0u; }
    } else {                            // ---- Z role: numpy-exact pairwise znorm
        const int t = (int)((blockIdx.x - 1024) * 256 + threadIdx.x);   // 0..65535
        const int row = t >> 2, blk = t & 3;
        const float4* p = (const float4*)(z + (size_t)row * DDIM + blk * 128);
        ushort* zo = zh + (size_t)row * DDIM + blk * 128;
        float4 v0 = p[0], v1 = p[1];
        {
            uint4 w; w.x = pack2(v0.x, v0.y); w.y = pack2(v0.z, v0.w);
            w.z = pack2(v1.x, v1.y); w.w = pack2(v1.z, v1.w);
            *(uint4*)zo = w;
        }
        float r[8];
        r[0] = sqr_rn(v0.x); r[1] = sqr_rn(v0.y); r[2] = sqr_rn(v0.z); r[3] = sqr_rn(v0.w);
        r[4] = sqr_rn(v1.x); r[5] = sqr_rn(v1.y); r[6] = sqr_rn(v1.z); r[7] = sqr_rn(v1.w);
        #pragma unroll
        for (int i = 1; i < 16; ++i) {
            v0 = p[2 * i]; v1 = p[2 * i + 1];
            uint4 w; w.x = pack2(v0.x, v0.y); w.y = pack2(v0.z, v0.w);
            w.z = pack2(v1.x, v1.y); w.w = pack2(v1.z, v1.w);
            *(uint4*)(zo + i * 8) = w;
            r[0] = __fadd_rn(r[0], sqr_rn(v0.x)); r[1] = __fadd_rn(r[1], sqr_rn(v0.y));
            r[2] = __fadd_rn(r[2], sqr_rn(v0.z)); r[3] = __fadd_rn(r[3], sqr_rn(v0.w));
            r[4] = __fadd_rn(r[4], sqr_rn(v1.x)); r[5] = __fadd_rn(r[5], sqr_rn(v1.y));
            r[6] = __fadd_rn(r[6], sqr_rn(v1.z)); r[7] = __fadd_rn(r[7], sqr_rn(v1.w));
        }
        const float B = __fadd_rn(__fadd_rn(__fadd_rn(r[0], r[1]), __fadd_rn(r[2], r[3])),
                                  __fadd_rn(__fadd_rn(r[4], r[5]), __fadd_rn(r[6], r[7])));
        const float s01 = __fadd_rn(B, __shfl_xor(B, 1));     // in-wave quad reduce
        const float zn  = __fadd_rn(s01, __shfl_xor(s01, 2)); // ((B0+B1)+(B2+B3))
        if (blk == 0) znorm[row] = zn;
    }
}

// ---------------- kernel 2: bf16 MFMA GEMM, 64x128 wave tile, dbuf b128 staging --------
// grid (128, 16), block 256 = 4 waves (2 row-halves x 2 col-halves of a 128x256 tile).
// Wave tile 64x128: 12 fragment reads feed 32 MFMAs per K-step (vs 8/16 at 64x64) —
// 25% less LDS traffic per FLOP, 2x MFMA per barrier. BK=32, dbuf 2x24KB.
// Contiguous-k fragment layout (R13-verified content): chunk = 16 rows x 32 k, lane l
// holds row 16g+(l&15), k = kb+8*(l>>4)+{0..7} -> staging is one global uint4 load +
// one ds_write_b128 per 16B slot (contiguous per chunk, conflict-free), frag read is
// one ds_read_b128. Same k-permutation for A and B => dot preserved.
// Per-(fi,fj) chain: 16 sequential K-step MFMAs, ascending k => absmax 0 preserved.
// Epilogue straight-line (R18): packed uint2 sbuf stores + branch-free rowblkmin.
__global__ __launch_bounds__(256) void k_mfma(const ushort* __restrict__ zh,
                                              const ushort* __restrict__ eh,
                                              const float* __restrict__ bnorm,
                                              ushort* __restrict__ sbuf,
                                              float* __restrict__ rowblkmin) {
    __shared__ ushort L[2][12288];   // per buf: A chunks [0,4096), B chunks [4096,12288)
    const int tid = threadIdx.x;
    const int lane = tid & 63;
    const int w = tid >> 6;
    const int warow = (w >> 1) * 64;          // 0 | 64
    const int wacol = (w & 1) * 128;          // 0 | 128
    const int rbase = blockIdx.x * 128, cbase = blockIdx.y * 256;
    const int r16 = lane & 15, g4 = (lane >> 4) * 4;

    // staging slots: A slots tid, tid+256 (of 512); B slots tid, +256, +512, +768 (of 1024)
    // slot s: chunk=s>>6, l=s&63 -> row 16*(s>>6)+(l&15), k8=((s>>4)&3)*8, LDS off s*8
    const int sA0 = tid, sA1 = tid + 256;
    #define GSRC(base, tile, s) ((base) + (size_t)((tile) + 16 * ((s) >> 6) + ((s) & 15)) * DDIM + (((s) >> 4) & 3) * 8)
    const ushort* gA0 = GSRC(zh, rbase, sA0);
    const ushort* gA1 = GSRC(zh, rbase, sA1);
    const ushort* gB0 = GSRC(eh, cbase, tid);
    const ushort* gB1 = GSRC(eh, cbase, tid + 256);
    const ushort* gB2 = GSRC(eh, cbase, tid + 512);
    const ushort* gB3 = GSRC(eh, cbase, tid + 768);
    #undef GSRC

    f32x4 acc[4][8];
    #pragma unroll
    for (int i = 0; i < 4; ++i)
        #pragma unroll
        for (int j = 0; j < 8; ++j) acc[i][j] = (f32x4){0.f, 0.f, 0.f, 0.f};

    // prologue: stage tile 0 into buf 0
    {
        const uint4 a0 = *(const uint4*)gA0, a1 = *(const uint4*)gA1;
        const uint4 b0 = *(const uint4*)gB0, b1 = *(const uint4*)gB1;
        const uint4 b2 = *(const uint4*)gB2, b3 = *(const uint4*)gB3;
        *(uint4*)&L[0][(size_t)sA0 * 8] = a0;
        *(uint4*)&L[0][(size_t)sA1 * 8] = a1;
        *(uint4*)&L[0][4096 + (size_t)tid * 8] = b0;
        *(uint4*)&L[0][4096 + (size_t)(tid + 256) * 8] = b1;
        *(uint4*)&L[0][4096 + (size_t)(tid + 512) * 8] = b2;
        *(uint4*)&L[0][4096 + (size_t)(tid + 768) * 8] = b3;
    }
    __syncthreads();

    for (int kb = 0; kb < DDIM; kb += 32) {
        const int cur = (kb >> 5) & 1;
        const bool more = (kb + 32 < DDIM);
        uint4 na0, na1, nb0, nb1, nb2, nb3;
        if (more) {     // early-issue next tile: latency hides under 32 MFMAs
            na0 = *(const uint4*)(gA0 + kb + 32);
            na1 = *(const uint4*)(gA1 + kb + 32);
            nb0 = *(const uint4*)(gB0 + kb + 32);
            nb1 = *(const uint4*)(gB1 + kb + 32);
            nb2 = *(const uint4*)(gB2 + kb + 32);
            nb3 = *(const uint4*)(gB3 + kb + 32);
        }
        bf16x8 af[4], bf[8];
        #pragma unroll
        for (int f = 0; f < 4; ++f)
            af[f] = *(const bf16x8*)&L[cur][(size_t)(((warow >> 4) + f) * 512 + lane * 8)];
        #pragma unroll
        for (int f = 0; f < 8; ++f)
            bf[f] = *(const bf16x8*)&L[cur][(size_t)(4096 + ((wacol >> 4) + f) * 512 + lane * 8)];
        #pragma unroll
        for (int fi = 0; fi < 4; ++fi)
            #pragma unroll
            for (int fj = 0; fj < 8; ++fj)
                acc[fi][fj] = __builtin_amdgcn_mfma_f32_16x16x32_bf16(
                    af[fi], bf[fj], acc[fi][fj], 0, 0, 0);
        if (more) {     // stage tile t+1 (its readers finished before the prev barrier)
            *(uint4*)&L[cur ^ 1][(size_t)sA0 * 8] = na0;
            *(uint4*)&L[cur ^ 1][(size_t)sA1 * 8] = na1;
            *(uint4*)&L[cur ^ 1][4096 + (size_t)tid * 8] = nb0;
            *(uint4*)&L[cur ^ 1][4096 + (size_t)(tid + 256) * 8] = nb1;
            *(uint4*)&L[cur ^ 1][4096 + (size_t)(tid + 512) * 8] = nb2;
            *(uint4*)&L[cur ^ 1][4096 + (size_t)(tid + 768) * 8] = nb3;
            __syncthreads();
        }
    }

    // C/D layout: value (fi,fj,r) -> row = warow+fi*16+g4+r, col = wacol+fj*16+r16
    float bn[8];
    #pragma unroll
    for (int fj = 0; fj < 8; ++fj) bn[fj] = bnorm[cbase + wacol + fj * 16 + r16];

    #pragma unroll
    for (int fi = 0; fi < 4; ++fi) {
        #pragma unroll
        for (int r = 0; r < 4; ++r) {
            const int row = rbase + warow + fi * 16 + g4 + r;
            float s[8];
            #pragma unroll
            for (int fj = 0; fj < 8; ++fj) s[fj] = fmaf(-2.f, acc[fi][fj][r], bn[fj]);
            uint2* sp = (uint2*)(sbuf + (size_t)row * NE + cbase + wacol);
            sp[r16] = make_uint2(pack2(s[0], s[1]), pack2(s[2], s[3]));
            uint2* sp2 = (uint2*)(sbuf + (size_t)row * NE + cbase + wacol + 64);
            sp2[r16] = make_uint2(pack2(s[4], s[5]), pack2(s[6], s[7]));
            float mlo = fminf(fminf(s[0], s[1]), fminf(s[2], s[3]));
            float mhi = fminf(fminf(s[4], s[5]), fminf(s[6], s[7]));
            #pragma unroll
            for (int x = 1; x < 16; x <<= 1) {
                mlo = fminf(mlo, __shfl_xor(mlo, x));
                mhi = fminf(mhi, __shfl_xor(mhi, x));
            }
            if (r16 == 0) {
                const size_t base = (size_t)row * 64 + blockIdx.y * 4 + (w & 1) * 2;
                rowblkmin[base]     = mlo;
                rowblkmin[base + 1] = mhi;
            }
        }
    }
}

// ---------------- exact numpy chain: sequential ascending-k FMA + exact bucketing ------
__device__ __forceinline__ unsigned long long exact_key(const float4* __restrict__ zp4,
                                                        const float* __restrict__ emb,
                                                        const float* __restrict__ bnorm,
                                                        float zn, int c) {
    const float4* ep4 = (const float4*)(emb + (size_t)c * DDIM);
    float acc = 0.f;
    #pragma unroll 8
    for (int q = 0; q < DDIM / 4; ++q) {
        const float4 zv = zp4[q];
        const float4 ev = ep4[q];
        acc = fmaf(zv.x, ev.x, acc);
        acc = fmaf(zv.y, ev.y, acc);
        acc = fmaf(zv.z, ev.z, acc);
        acc = fmaf(zv.w, ev.w, acc);
    }
    const float s = __fsub_rn(__fadd_rn(zn, bnorm[c]), __fmul_rn(2.f, acc));
    return ((unsigned long long)__float_as_uint(s) << 32) | (unsigned)c;
}

// ---------------- kernel 3: guided pick + exact resolve + gather + STE ----------------
// one wave per row; reads rowblkmin (4MB) + only flagged sbuf segments (~1.3 x 128B/row);
// candidates live only in per-wave LDS (no cross-block races); writes out.
// sbuf in-64-block permutation: col = b*64 + (i&3)*16 + (i>>2).
__global__ void k_pg(const ushort* __restrict__ sbuf, const float* __restrict__ rowblkmin,
                     const float* __restrict__ z, const float* __restrict__ emb,
                     const float* __restrict__ znorm, const float* __restrict__ bnorm,
                     float* __restrict__ out, unsigned* __restrict__ counts,
                     float* __restrict__ d2buf) {
    __shared__ int candL[4][MAXC];
    __shared__ unsigned cntL[4];
    const int lane = threadIdx.x & 63;
    const int w = threadIdx.x >> 6;
    const int row = blockIdx.x * 4 + w;
    if (threadIdx.x < 4) cntL[threadIdx.x] = 0u;
    __syncthreads();

    const float bm = rowblkmin[(size_t)row * 64 + lane];
    float gmin = bm;
    #pragma unroll
    for (int m = 32; m; m >>= 1) gmin = fminf(gmin, __shfl_xor(gmin, m));
    const float thr = gmin + MARGIN;
    unsigned long long bmask = __ballot(bm <= thr);   // expected ~1.3 blocks
    while (bmask) {
        const int b = __builtin_ctzll(bmask); bmask &= bmask - 1;
        const float val = __uint_as_float(
            (unsigned)sbuf[(size_t)row * NE + b * 64 + lane] << 16);
        if (val <= thr) {
            const unsigned slot = atomicAdd(&cntL[w], 1u);
            if (slot < MAXC)
                candL[w][slot] = b * 64 + (lane & 3) * 16 + (lane >> 2);
        }
    }
    __syncthreads();

    const int cnt = (int)cntL[w];
    int id;
    if (cnt == 1) {
        id = candL[w][0] & (NE - 1);
    } else {
        const float zn = znorm[row];
        const float4* zp4 = (const float4*)(z + (size_t)row * DDIM);
        unsigned long long best = ~0ULL;
        if (cnt >= 2 && cnt <= MAXC) {
            if (lane < cnt)
                best = exact_key(zp4, emb, bnorm, zn, candL[w][lane] & (NE - 1));
        } else {             // cnt==0 (impossible) or overflow: exact scan of all codes
            for (int c = lane; c < NE; c += 64) {
                const unsigned long long k = exact_key(zp4, emb, bnorm, zn, c);
                if (k < best) best = k;
            }
        }
        #pragma unroll
        for (int m = 32; m; m >>= 1) {
            const unsigned long long ov = __shfl_xor(best, m);
            if (ov < best) best = ov;
        }
        id = (int)(__shfl(best, 0) & (unsigned long long)(NE - 1));
    }

    const float* zp = z + (size_t)row * DDIM;
    const float* ep = emb + (size_t)id * DDIM;
    float* op = out + 1 + (size_t)row * DDIM;
    float d2 = 0.f;
    #pragma unroll
    for (int m = 0; m < 8; ++m) {
        const int k = m * 64 + lane;
        const float e = ep[k];
        const float zv = zp[k];
        const float t = e - zv;          // two-step rounding matches reference STE
        op[k] = zv + t;
        d2 = fmaf(t, t, d2);
    }
    #pragma unroll
    for (int m = 32; m; m >>= 1) d2 += __shfl_xor(d2, m);
    if (lane == 0) {
        atomicAdd(&counts[id], 1u);
        d2buf[row] = d2;
        out[1 + (size_t)NZ + row] = (float)id;
    }
}

// ---------------- kernel 4: finalize loss + perplexity ----------------
__global__ void k_final(const float* __restrict__ d2buf, const unsigned* __restrict__ counts,
                        float* __restrict__ out) {
    __shared__ double sh[256];
    __shared__ float  shf[256];
    const int tid = threadIdx.x;
    double ent = 0.0;
    for (int i = tid; i < NE; i += 256) {
        const double p = (double)counts[i] / (double)NROWS;
        ent += p * log(p + 1e-10);
    }
    float sse = 0.f;
    for (int i = tid; i < NROWS; i += 256) sse += d2buf[i];
    sh[tid] = ent; shf[tid] = sse;
    __syncthreads();
    for (int s = 128; s; s >>= 1) {
        if (tid < s) { sh[tid] += sh[tid + s]; shf[tid] += shf[tid + s]; }
        __syncthreads();
    }
    if (tid == 0) {
        out[0] = 1.25f * (shf[0] / (float)NZ);
        out[1 + (size_t)NZ + NROWS] = (float)exp(-sh[0]);
    }
}

extern "C" void kernel_launch(void* const* d_in, const int* in_sizes, int n_in,
                              void* d_out, int out_size, void* d_ws, size_t ws_size,
                              hipStream_t stream) {
    const float* z   = (const float*)d_in[0];
    const float* emb = (const float*)d_in[1];
    float* out = (float*)d_out;
    char* ws = (char*)d_ws;

    // zh/eh live inside out[1..NZ]: written by k_prep, read by k_mfma, and only
    // k_pg (strictly later in stream order) writes out -> no overlap anywhere.
    ushort* zh = (ushort*)(out + 4);                       // 16 MB
    ushort* eh = (ushort*)(out + 4 + 4194304);             //  4 MB

    size_t off = 0;
    float*    bnorm  = (float*)(ws + off); off += (size_t)NE * 4;          // 16KB
    unsigned* counts = (unsigned*)(ws + off); off += (size_t)NE * 4;       // 16KB
    float*    d2buf  = (float*)(ws + off); off += (size_t)NROWS * 4;       // 64KB
    float*    znorm  = (float*)(ws + off); off += (size_t)NROWS * 4;       // 64KB
    ushort*   sbuf   = (ushort*)(ws + off); off += (size_t)NROWS * NE * 2; // 128MB
    float*    rowblkmin = (float*)(ws + off); off += (size_t)NROWS * 64 * 4; // 4MB
    // total ~132.5MB == proven footprint

    k_prep<<<1280, 256, 0, stream>>>(z, emb, zh, eh, znorm, bnorm, counts);
    k_mfma<<<dim3(NROWS / 128, NE / 256), 256, 0, stream>>>(zh, eh, bnorm, sbuf, rowblkmin);
    k_pg<<<NROWS / 4, 256, 0, stream>>>(sbuf, rowblkmin, z, emb, znorm, bnorm, out, counts, d2buf);
    k_final<<<1, 256, 0, stream>>>(d2buf, counts, out);
}

// Round 24
// 295.229 us; speedup vs baseline: 2.9270x; 1.0846x over previous
//
#include <hip/hip_runtime.h>
#include <math.h>

#define NROWS 16384      // 32*512
#define DDIM  512
#define NE    4096
#define NZ    (NROWS * DDIM)
#define MAXC  64             // per-row kept-candidate cap (expected ~2)
#define MARGIN 2e-3f         // >= bound 2E + bucket + bf16 rounds ~ 1.4e-3

typedef __attribute__((ext_vector_type(8))) short bf16x8;
typedef __attribute__((ext_vector_type(4))) float f32x4;

__device__ __forceinline__ float sqr_rn(float x) { return __fmul_rn(x, x); }
__device__ __forceinline__ ushort f2bf(float f) {   // RNE f32->bf16
    const unsigned u = __float_as_uint(f);
    return (ushort)((u + 0x7fffu + ((u >> 16) & 1u)) >> 16);
}
__device__ __forceinline__ unsigned pack2(float a, float b) {
    return (unsigned)f2bf(a) | ((unsigned)f2bf(b) << 16);
}

// ---------------- kernel 1: fused prep (Z: numpy-exact znorm + bf16; E: bnorm + bf16) --
__global__ void k_prep(const float* __restrict__ z, const float* __restrict__ emb,
                       ushort* __restrict__ zh, ushort* __restrict__ eh,
                       float* __restrict__ znorm, float* __restrict__ bnorm,
                       unsigned* __restrict__ counts) {
    if (blockIdx.x < 1024) {            // ---- E role: 4096 codes x 1 wave
        const int lane = threadIdx.x & 63;
        const int c = (int)((blockIdx.x * 256 + threadIdx.x) >> 6);
        const float4* p = (const float4*)(emb + (size_t)c * DDIM);
        const float4 v0 = p[lane * 2], v1 = p[lane * 2 + 1];
        uint4 w; w.x = pack2(v0.x, v0.y); w.y = pack2(v0.z, v0.w);
        w.z = pack2(v1.x, v1.y); w.w = pack2(v1.z, v1.w);
        *(uint4*)(eh + (size_t)c * DDIM + lane * 8) = w;
        float s = v0.x*v0.x + v0.y*v0.y + v0.z*v0.z + v0.w*v0.w
                + v1.x*v1.x + v1.y*v1.y + v1.z*v1.z + v1.w*v1.w;
        #pragma unroll
        for (int m = 32; m; m >>= 1) s += __shfl_xor(s, m);
        if (lane == 0) { bnorm[c] = s; counts[c] = 0u; }
    } else {                            // ---- Z role: numpy-exact pairwise znorm
        const int t = (int)((blockIdx.x - 1024) * 256 + threadIdx.x);   // 0..65535
        const int row = t >> 2, blk = t & 3;
        const float4* p = (const float4*)(z + (size_t)row * DDIM + blk * 128);
        ushort* zo = zh + (size_t)row * DDIM + blk * 128;
        float4 v0 = p[0], v1 = p[1];
        {
            uint4 w; w.x = pack2(v0.x, v0.y); w.y = pack2(v0.z, v0.w);
            w.z = pack2(v1.x, v1.y); w.w = pack2(v1.z, v1.w);
            *(uint4*)zo = w;
        }
        float r[8];
        r[0] = sqr_rn(v0.x); r[1] = sqr_rn(v0.y); r[2] = sqr_rn(v0.z); r[3] = sqr_rn(v0.w);
        r[4] = sqr_rn(v1.x); r[5] = sqr_rn(v1.y); r[6] = sqr_rn(v1.z); r[7] = sqr_rn(v1.w);
        #pragma unroll
        for (int i = 1; i < 16; ++i) {
            v0 = p[2 * i]; v1 = p[2 * i + 1];
            uint4 w; w.x = pack2(v0.x, v0.y); w.y = pack2(v0.z, v0.w);
            w.z = pack2(v1.x, v1.y); w.w = pack2(v1.z, v1.w);
            *(uint4*)(zo + i * 8) = w;
            r[0] = __fadd_rn(r[0], sqr_rn(v0.x)); r[1] = __fadd_rn(r[1], sqr_rn(v0.y));
            r[2] = __fadd_rn(r[2], sqr_rn(v0.z)); r[3] = __fadd_rn(r[3], sqr_rn(v0.w));
            r[4] = __fadd_rn(r[4], sqr_rn(v1.x)); r[5] = __fadd_rn(r[5], sqr_rn(v1.y));
            r[6] = __fadd_rn(r[6], sqr_rn(v1.z)); r[7] = __fadd_rn(r[7], sqr_rn(v1.w));
        }
        const float B = __fadd_rn(__fadd_rn(__fadd_rn(r[0], r[1]), __fadd_rn(r[2], r[3])),
                                  __fadd_rn(__fadd_rn(r[4], r[5]), __fadd_rn(r[6], r[7])));
        const float s01 = __fadd_rn(B, __shfl_xor(B, 1));     // in-wave quad reduce
        const float zn  = __fadd_rn(s01, __shfl_xor(s01, 2)); // ((B0+B1)+(B2+B3))
        if (blk == 0) znorm[row] = zn;
    }
}

// ---------------- kernel 2: bf16 MFMA GEMM, dbuf + slot-based b128 staging -------------
// grid (128, 32), block 256 = 4 waves (2x2 of 64x64). Tile 128x128, BK=32, 32KB LDS.
// R20 counters arithmetic: LDS-bound, and 16 ds_write_b64/thread (transpose scatter) was
// half the LDS cost. R23-verified slot staging: slot s = (chunk s>>6, lane s&63); lane
// holds row 16*(s>>6)+(s&15), k8 = ((s>>4)&3)*8 -> global uint4 load + ONE contiguous
// ds_write_b128 (4/thread vs 16 b64). Fragment content (row,k per lane) identical to all
// passing rounds -> MFMA chain byte-identical -> absmax 0 preserved.
// Loop = R20-verified dbuf (1 barrier/K-step) + early-issued next-tile loads.
// Epilogue straight-line (R18): packed uint2 sbuf stores + branch-free rowblkmin.
__global__ __launch_bounds__(256) void k_mfma(const ushort* __restrict__ zh,
                                              const ushort* __restrict__ eh,
                                              const float* __restrict__ bnorm,
                                              ushort* __restrict__ sbuf,
                                              float* __restrict__ rowblkmin) {
    __shared__ ushort L[2][8192];   // per buf 16KB: A slots [0,4096), B slots [4096,8192)
    const int tid = threadIdx.x;
    const int lane = tid & 63;
    const int w = tid >> 6;
    const int wrow = (w >> 1) * 64, wcol = (w & 1) * 64;
    const int rbase = blockIdx.x * 128, cbase = blockIdx.y * 128;
    const int r16 = lane & 15, g4 = (lane >> 4) * 4;

    // staging: A slots tid, tid+256 (of 512); B slots tid, tid+256
    const int sA0 = tid, sA1 = tid + 256;
    #define GSRC(base, tile, s) ((base) + (size_t)((tile) + 16 * ((s) >> 6) + ((s) & 15)) * DDIM + (((s) >> 4) & 3) * 8)
    const ushort* gA0 = GSRC(zh, rbase, sA0);
    const ushort* gA1 = GSRC(zh, rbase, sA1);
    const ushort* gB0 = GSRC(eh, cbase, sA0);
    const ushort* gB1 = GSRC(eh, cbase, sA1);
    #undef GSRC

    f32x4 acc[4][4];
    #pragma unroll
    for (int i = 0; i < 4; ++i)
        #pragma unroll
        for (int j = 0; j < 4; ++j) acc[i][j] = (f32x4){0.f, 0.f, 0.f, 0.f};

    // prologue: stage tile 0 into buf 0 (contiguous b128 writes)
    {
        const uint4 a0 = *(const uint4*)gA0, a1 = *(const uint4*)gA1;
        const uint4 b0 = *(const uint4*)gB0, b1 = *(const uint4*)gB1;
        *(uint4*)&L[0][(size_t)sA0 * 8]        = a0;
        *(uint4*)&L[0][(size_t)sA1 * 8]        = a1;
        *(uint4*)&L[0][4096 + (size_t)sA0 * 8] = b0;
        *(uint4*)&L[0][4096 + (size_t)sA1 * 8] = b1;
    }
    __syncthreads();

    for (int kb = 0; kb < DDIM; kb += 32) {
        const int cur = (kb >> 5) & 1;
        const bool more = (kb + 32 < DDIM);
        uint4 na0, na1, nb0, nb1;
        if (more) {     // early-issue next tile: latency hides under 16 MFMAs
            na0 = *(const uint4*)(gA0 + kb + 32);
            na1 = *(const uint4*)(gA1 + kb + 32);
            nb0 = *(const uint4*)(gB0 + kb + 32);
            nb1 = *(const uint4*)(gB1 + kb + 32);
        }
        bf16x8 af[4], bf[4];
        #pragma unroll
        for (int f = 0; f < 4; ++f) {
            af[f] = *(const bf16x8*)&L[cur][(size_t)(((wrow >> 4) + f) * 512 + lane * 8)];
            bf[f] = *(const bf16x8*)&L[cur][(size_t)(4096 + ((wcol >> 4) + f) * 512 + lane * 8)];
        }
        #pragma unroll
        for (int fi = 0; fi < 4; ++fi)
            #pragma unroll
            for (int fj = 0; fj < 4; ++fj)
                acc[fi][fj] = __builtin_amdgcn_mfma_f32_16x16x32_bf16(
                    af[fi], bf[fj], acc[fi][fj], 0, 0, 0);
        if (more) {     // stage tile t+1 (its readers finished before the prev barrier)
            *(uint4*)&L[cur ^ 1][(size_t)sA0 * 8]        = na0;
            *(uint4*)&L[cur ^ 1][(size_t)sA1 * 8]        = na1;
            *(uint4*)&L[cur ^ 1][4096 + (size_t)sA0 * 8] = nb0;
            *(uint4*)&L[cur ^ 1][4096 + (size_t)sA1 * 8] = nb1;
            __syncthreads();
        }
    }

    // C/D layout: value (fi,fj,r) -> row = wrow+fi*16+g4+r, col = wcol+fj*16+r16
    float bn[4];
    #pragma unroll
    for (int fj = 0; fj < 4; ++fj) bn[fj] = bnorm[cbase + wcol + fj * 16 + r16];

    #pragma unroll
    for (int fi = 0; fi < 4; ++fi) {
        #pragma unroll
        for (int r = 0; r < 4; ++r) {
            const int row = rbase + wrow + fi * 16 + g4 + r;
            float s[4];
            #pragma unroll
            for (int fj = 0; fj < 4; ++fj) s[fj] = fmaf(-2.f, acc[fi][fj][r], bn[fj]);
            uint2* sp = (uint2*)(sbuf + (size_t)row * NE + cbase + wcol);
            sp[r16] = make_uint2(pack2(s[0], s[1]), pack2(s[2], s[3]));
            float m = fminf(fminf(s[0], s[1]), fminf(s[2], s[3]));
            #pragma unroll
            for (int x = 1; x < 16; x <<= 1) m = fminf(m, __shfl_xor(m, x));  // 16-lane grp
            if (r16 == 0)
                rowblkmin[(size_t)row * 64 + blockIdx.y * 2 + (w & 1)] = m;
        }
    }
}

// ---------------- exact numpy chain: sequential ascending-k FMA + exact bucketing ------
__device__ __forceinline__ unsigned long long exact_key(const float4* __restrict__ zp4,
                                                        const float* __restrict__ emb,
                                                        const float* __restrict__ bnorm,
                                                        float zn, int c) {
    const float4* ep4 = (const float4*)(emb + (size_t)c * DDIM);
    float acc = 0.f;
    #pragma unroll 8
    for (int q = 0; q < DDIM / 4; ++q) {
        const float4 zv = zp4[q];
        const float4 ev = ep4[q];
        acc = fmaf(zv.x, ev.x, acc);
        acc = fmaf(zv.y, ev.y, acc);
        acc = fmaf(zv.z, ev.z, acc);
        acc = fmaf(zv.w, ev.w, acc);
    }
    const float s = __fsub_rn(__fadd_rn(zn, bnorm[c]), __fmul_rn(2.f, acc));
    return ((unsigned long long)__float_as_uint(s) << 32) | (unsigned)c;
}

// ---------------- kernel 3: guided pick + exact resolve + gather + STE ----------------
// one wave per row; reads rowblkmin (4MB) + only flagged sbuf segments (~1.3 x 128B/row);
// candidates live only in per-wave LDS (no cross-block races); writes out.
// sbuf in-64-block permutation: col = b*64 + (i&3)*16 + (i>>2).
__global__ void k_pg(const ushort* __restrict__ sbuf, const float* __restrict__ rowblkmin,
                     const float* __restrict__ z, const float* __restrict__ emb,
                     const float* __restrict__ znorm, const float* __restrict__ bnorm,
                     float* __restrict__ out, unsigned* __restrict__ counts,
                     float* __restrict__ d2buf) {
    __shared__ int candL[4][MAXC];
    __shared__ unsigned cntL[4];
    const int lane = threadIdx.x & 63;
    const int w = threadIdx.x >> 6;
    const int row = blockIdx.x * 4 + w;
    if (threadIdx.x < 4) cntL[threadIdx.x] = 0u;
    __syncthreads();

    const float bm = rowblkmin[(size_t)row * 64 + lane];
    float gmin = bm;
    #pragma unroll
    for (int m = 32; m; m >>= 1) gmin = fminf(gmin, __shfl_xor(gmin, m));
    const float thr = gmin + MARGIN;
    unsigned long long bmask = __ballot(bm <= thr);   // expected ~1.3 blocks
    while (bmask) {
        const int b = __builtin_ctzll(bmask); bmask &= bmask - 1;
        const float val = __uint_as_float(
            (unsigned)sbuf[(size_t)row * NE + b * 64 + lane] << 16);
        if (val <= thr) {
            const unsigned slot = atomicAdd(&cntL[w], 1u);
            if (slot < MAXC)
                candL[w][slot] = b * 64 + (lane & 3) * 16 + (lane >> 2);
        }
    }
    __syncthreads();

    const int cnt = (int)cntL[w];
    int id;
    if (cnt == 1) {
        id = candL[w][0] & (NE - 1);
    } else {
        const float zn = znorm[row];
        const float4* zp4 = (const float4*)(z + (size_t)row * DDIM);
        unsigned long long best = ~0ULL;
        if (cnt >= 2 && cnt <= MAXC) {
            if (lane < cnt)
                best = exact_key(zp4, emb, bnorm, zn, candL[w][lane] & (NE - 1));
        } else {             // cnt==0 (impossible) or overflow: exact scan of all codes
            for (int c = lane; c < NE; c += 64) {
                const unsigned long long k = exact_key(zp4, emb, bnorm, zn, c);
                if (k < best) best = k;
            }
        }
        #pragma unroll
        for (int m = 32; m; m >>= 1) {
            const unsigned long long ov = __shfl_xor(best, m);
            if (ov < best) best = ov;
        }
        id = (int)(__shfl(best, 0) & (unsigned long long)(NE - 1));
    }

    const float* zp = z + (size_t)row * DDIM;
    const float* ep = emb + (size_t)id * DDIM;
    float* op = out + 1 + (size_t)row * DDIM;
    float d2 = 0.f;
    #pragma unroll
    for (int m = 0; m < 8; ++m) {
        const int k = m * 64 + lane;
        const float e = ep[k];
        const float zv = zp[k];
        const float t = e - zv;          // two-step rounding matches reference STE
        op[k] = zv + t;
        d2 = fmaf(t, t, d2);
    }
    #pragma unroll
    for (int m = 32; m; m >>= 1) d2 += __shfl_xor(d2, m);
    if (lane == 0) {
        atomicAdd(&counts[id], 1u);
        d2buf[row] = d2;
        out[1 + (size_t)NZ + row] = (float)id;
    }
}

// ---------------- kernel 4: finalize loss + perplexity ----------------
__global__ void k_final(const float* __restrict__ d2buf, const unsigned* __restrict__ counts,
                        float* __restrict__ out) {
    __shared__ double sh[256];
    __shared__ float  shf[256];
    const int tid = threadIdx.x;
    double ent = 0.0;
    for (int i = tid; i < NE; i += 256) {
        const double p = (double)counts[i] / (double)NROWS;
        ent += p * log(p + 1e-10);
    }
    float sse = 0.f;
    for (int i = tid; i < NROWS; i += 256) sse += d2buf[i];
    sh[tid] = ent; shf[tid] = sse;
    __syncthreads();
    for (int s = 128; s; s >>= 1) {
        if (tid < s) { sh[tid] += sh[tid + s]; shf[tid] += shf[tid + s]; }
        __syncthreads();
    }
    if (tid == 0) {
        out[0] = 1.25f * (shf[0] / (float)NZ);
        out[1 + (size_t)NZ + NROWS] = (float)exp(-sh[0]);
    }
}

extern "C" void kernel_launch(void* const* d_in, const int* in_sizes, int n_in,
                              void* d_out, int out_size, void* d_ws, size_t ws_size,
                              hipStream_t stream) {
    const float* z   = (const float*)d_in[0];
    const float* emb = (const float*)d_in[1];
    float* out = (float*)d_out;
    char* ws = (char*)d_ws;

    // zh/eh live inside out[1..NZ]: written by k_prep, read by k_mfma, and only
    // k_pg (strictly later in stream order) writes out -> no overlap anywhere.
    ushort* zh = (ushort*)(out + 4);                       // 16 MB
    ushort* eh = (ushort*)(out + 4 + 4194304);             //  4 MB

    size_t off = 0;
    float*    bnorm  = (float*)(ws + off); off += (size_t)NE * 4;          // 16KB
    unsigned* counts = (unsigned*)(ws + off); off += (size_t)NE * 4;       // 16KB
    float*    d2buf  = (float*)(ws + off); off += (size_t)NROWS * 4;       // 64KB
    float*    znorm  = (float*)(ws + off); off += (size_t)NROWS * 4;       // 64KB
    ushort*   sbuf   = (ushort*)(ws + off); off += (size_t)NROWS * NE * 2; // 128MB
    float*    rowblkmin = (float*)(ws + off); off += (size_t)NROWS * 64 * 4; // 4MB
    // total ~132.5MB == proven footprint

    k_prep<<<1280, 256, 0, stream>>>(z, emb, zh, eh, znorm, bnorm, counts);
    k_mfma<<<dim3(NROWS / 128, NE / 128), 256, 0, stream>>>(zh, eh, bnorm, sbuf, rowblkmin);
    k_pg<<<NROWS / 4, 256, 0, stream>>>(sbuf, rowblkmin, z, emb, znorm, bnorm, out, counts, d2buf);
    k_final<<<1, 256, 0, stream>>>(d2buf, counts, out);
}